// Round 9
// baseline (376.445 us; speedup 1.0000x reference)
//
#include <hip/hip_runtime.h>
#include <hip/hip_bf16.h>
#include <math.h>

// Problem constants
#define SEQ   128
#define BSZ   64
#define NH    256
#define NT    50000
#define NSAMP 32
#define SB    8192      // SEQ*BSZ
#define TEMPC 65.0f

typedef float f32x2 __attribute__((ext_vector_type(2)));

__device__ __forceinline__ float rlf(float v, int lane) {
  return __uint_as_float(__builtin_amdgcn_readlane(__float_as_uint(v), lane));
}

// tanh(x) = 1 - 2/(exp(2x)+1); v_exp + v_rcp, ~1ulp, saturates correctly at +/-1
__device__ __forceinline__ float tanh_fast(float x) {
  float e = __expf(2.0f * x);
  return 1.0f - 2.0f * __builtin_amdgcn_rcpf(e + 1.0f);
}

// ---------------------------------------------------------------------------
// K0: transpose W_ih -> Wt (Wt[k*256+j] = W_ih[j*256+k]).
// ---------------------------------------------------------------------------
__global__ void k_prep(const float* __restrict__ W_ih, float* __restrict__ Wt) {
  const int k = blockIdx.x, j = threadIdx.x;
  Wt[k * 256 + j] = W_ih[j * 256 + k];
}

// ---------------------------------------------------------------------------
// K1: proj[v,j] = sum_k emb[v,k] * W_ih[j,k] + b_ih[j]   (M x 256 @ 256 x 256)
// Block: 512 thr = 8 waves; tile = 64 rows x 256 cols. Thread t owns
// 4 rows x 8 cols: rq = t&15 -> rows {rq,rq+16,rq+32,rq+48}, cg = t>>4 ->
// cols [8cg, 8cg+8). Per kk-pair: 4 VMEM dwordx4 (W) + 8 LDS b32 (A) per
// 32 pk-FMA -- 4x fewer VMEM instructions than 1row x 32col split,
// 4x W-register reuse, 16 independent FMA chains.
// A-tile in LDS stride 257: A-reads hit 16 distinct banks, 4-way
// same-address broadcast (free). W bytes/wave unchanged (dup lanes merge).
// ---------------------------------------------------------------------------
__global__ __launch_bounds__(512, 4) void k_proj(const float* __restrict__ A,
    const float* __restrict__ Wt, const float* __restrict__ bias,
    float* __restrict__ out, int M) {
  __shared__ float As[64 * 257];
  const int t = threadIdx.x;
  const int r0 = blockIdx.x * 64;

  // stage A tile: 64 rows x 256 cols (float4 loads, scalar LDS stores)
#pragma unroll
  for (int s = 0; s < 8; ++s) {
    int lin = t + s * 512;               // 0..4095
    int row = lin >> 6, kq = lin & 63;
    float4 v = make_float4(0.f, 0.f, 0.f, 0.f);
    if (r0 + row < M) v = ((const float4*)A)[(size_t)(r0 + row) * 64 + kq];
    float* d = &As[row * 257 + kq * 4];
    d[0] = v.x; d[1] = v.y; d[2] = v.z; d[3] = v.w;
  }
  __syncthreads();

  const int rq = t & 15;                 // base row
  const int cg = t >> 4;                 // col-group: cols [8cg, 8cg+8)
  const float* wp = Wt + 8 * cg;

  f32x2 acc[4][4];                       // [row m][col-pair c]
#pragma unroll
  for (int m = 0; m < 4; ++m)
#pragma unroll
    for (int c = 0; c < 4; ++c) acc[m][c] = (f32x2){0.f, 0.f};

  for (int kk = 0; kk < 256; kk += 2) {
    const float4* wr0 = (const float4*)(wp + (kk << 8));
    const float4* wr1 = (const float4*)(wp + ((kk + 1) << 8));
    float4 wa0 = wr0[0], wa1 = wr0[1];
    float4 wb0 = wr1[0], wb1 = wr1[1];
    f32x2 wA[4] = {{wa0.x, wa0.y}, {wa0.z, wa0.w}, {wa1.x, wa1.y}, {wa1.z, wa1.w}};
    f32x2 wB[4] = {{wb0.x, wb0.y}, {wb0.z, wb0.w}, {wb1.x, wb1.y}, {wb1.z, wb1.w}};
#pragma unroll
    for (int m = 0; m < 4; ++m) {
      float a0 = As[(rq + 16 * m) * 257 + kk];
      float a1 = As[(rq + 16 * m) * 257 + kk + 1];
      f32x2 a0p = {a0, a0}, a1p = {a1, a1};
#pragma unroll
      for (int c = 0; c < 4; ++c) {
        acc[m][c] = __builtin_elementwise_fma(a0p, wA[c], acc[m][c]);
        acc[m][c] = __builtin_elementwise_fma(a1p, wB[c], acc[m][c]);
      }
    }
  }
  __syncthreads();

  // scatter results to LDS, then coalesced global stores (+bias)
#pragma unroll
  for (int m = 0; m < 4; ++m)
#pragma unroll
    for (int c = 0; c < 4; ++c) {
      As[(rq + 16 * m) * 257 + 8 * cg + 2 * c]     = acc[m][c].x;
      As[(rq + 16 * m) * 257 + 8 * cg + 2 * c + 1] = acc[m][c].y;
    }
  __syncthreads();
#pragma unroll
  for (int s = 0; s < 32; ++s) {
    int lin = t + s * 512;               // 0..16383
    int row = lin >> 8, col = lin & 255;
    if (r0 + row < M)
      out[(size_t)(r0 + row) * 256 + col] = As[row * 257 + col] + bias[col];
  }
}

// ---------------------------------------------------------------------------
// K2: RNN scan, one block per batch row b. 512 thr = 8 waves, ONE barrier
// per step. Wave w owns k-slice [32w,32w+32); lane l holds W_hh cols
// {l,l+64,l+128,l+192} over that slice (f32x2-packed, 4 indep FMA chains).
// KEY: wave w only ever needs h[32w..32w+32) for its broadcasts, and its
// own lanes compute exactly those columns in the epilogue (jv = 32w+(l&31),
// lanes 32-63 duplicate). So h stays IN REGISTERS across steps -- no h-LDS
// buffer, no second barrier. part[] is double-buffered so the single
// barrier also covers buffer reuse (a wave cannot be 2 iterations ahead).
// Epilogue partial-combine: part[buf][w'][jv], bank = jv%32, conflict-free
// (lanes 32-63 same-address broadcast).
// Writes per step t: hU[t*64+b] (reused by K3), ro[t+1] = h_{t+1};
// new_hidden into d_out[1..] at the last step. x0 is deferred to k_loss.
// ---------------------------------------------------------------------------
__global__ __launch_bounds__(512, 2) void k_scan(const float* __restrict__ proj,
    const int* __restrict__ data, const float* __restrict__ W_hh,
    const float* __restrict__ b_hh, const float* __restrict__ hidden,
    float* __restrict__ ro, float* __restrict__ hU, float* __restrict__ out) {
  __shared__ float part[2][8][256];
  __shared__ int   ldata[128];
  const int t = threadIdx.x, b = blockIdx.x;
  const int l = t & 63, w = t >> 6, w32 = w * 32;
  const int jv = w32 + (l & 31);        // epilogue column this lane owns

  // per-lane W slices, packed as col-pairs sharing the same k:
  // w01[i] = {W[l][w32+i], W[l+64][w32+i]}, w23[i] = {W[l+128][..], W[l+192][..]}
  f32x2 w01[32], w23[32];
  {
    const float4* r0 = (const float4*)(W_hh + (size_t)(l)*256 + w32);
    const float4* r1 = (const float4*)(W_hh + (size_t)(l + 64) * 256 + w32);
    const float4* r2 = (const float4*)(W_hh + (size_t)(l + 128) * 256 + w32);
    const float4* r3 = (const float4*)(W_hh + (size_t)(l + 192) * 256 + w32);
#pragma unroll
    for (int i4 = 0; i4 < 8; ++i4) {
      float4 v0 = r0[i4], v1 = r1[i4], v2 = r2[i4], v3 = r3[i4];
      w01[4 * i4 + 0] = (f32x2){v0.x, v1.x}; w01[4 * i4 + 1] = (f32x2){v0.y, v1.y};
      w01[4 * i4 + 2] = (f32x2){v0.z, v1.z}; w01[4 * i4 + 3] = (f32x2){v0.w, v1.w};
      w23[4 * i4 + 0] = (f32x2){v2.x, v3.x}; w23[4 * i4 + 1] = (f32x2){v2.y, v3.y};
      w23[4 * i4 + 2] = (f32x2){v2.z, v3.z}; w23[4 * i4 + 3] = (f32x2){v2.w, v3.w};
    }
  }
  if (t < 128) ldata[t] = data[t * 64 + b];
  __syncthreads();                       // ldata ready

  float hv = hidden[b * 256 + jv];       // register-resident h (2-way dup)
  if (l < 32) ro[b * 256 + jv] = hv;     // ro[0] = hidden
  const float bhh = b_hh[jv];
  float xv = proj[(size_t)ldata[0] * 256 + jv];

  for (int st = 0; st < 128; ++st) {
    const int buf = st & 1;
    // dot: this wave's k-slice partial for cols (l, l+64, l+128, l+192);
    // h broadcasts come straight from lane registers (lanes 0-31 hold
    // h[w32..w32+32) computed by last step's epilogue).
    f32x2 a01a = {0.f, 0.f}, a01b = {0.f, 0.f};
    f32x2 a23a = {0.f, 0.f}, a23b = {0.f, 0.f};
#pragma unroll
    for (int i = 0; i < 32; i += 2) {
      float h0 = rlf(hv, i), h1 = rlf(hv, i + 1);
      f32x2 h0p = {h0, h0}, h1p = {h1, h1};
      a01a = __builtin_elementwise_fma(h0p, w01[i],     a01a);
      a23a = __builtin_elementwise_fma(h0p, w23[i],     a23a);
      a01b = __builtin_elementwise_fma(h1p, w01[i + 1], a01b);
      a23b = __builtin_elementwise_fma(h1p, w23[i + 1], a23b);
    }
    f32x2 a01 = a01a + a01b, a23 = a23a + a23b;
    part[buf][w][l]       = a01.x;
    part[buf][w][l + 64]  = a01.y;
    part[buf][w][l + 128] = a23.x;
    part[buf][w][l + 192] = a23.y;

    // prefetch next step's x for this lane's own column (hidden by barrier)
    float xvn = 0.f;
    if (st < 127) xvn = proj[(size_t)ldata[st + 1] * 256 + jv];

    __syncthreads();

    // every wave reduces its OWN h-slice columns; h never leaves registers
    float hu = ((part[buf][0][jv] + part[buf][1][jv])
              + (part[buf][2][jv] + part[buf][3][jv]))
             + ((part[buf][4][jv] + part[buf][5][jv])
              + (part[buf][6][jv] + part[buf][7][jv])) + bhh;
    float hn = tanh_fast(hu + xv);
    hv = hn;
    const int p = st * 64 + b;
    if (l < 32) {
      hU[(size_t)p * 256 + jv] = hu;
      ro[((size_t)p + 64) * 256 + jv] = hn;
      if (st == 127) out[1 + b * 256 + jv] = hn;   // new_hidden
    }
    xv = xvn;
  }
}

// ---------------------------------------------------------------------------
// K3: positives + negatives + per-column logsumexp. One wave per column p
// (4 waves/block). Lane l owns CONTIGUOUS cols 4l..4l+3 -> every per-row
// access is ONE global_load_dwordx4 (wave covers the 1KB row coalesced;
// 4x fewer VMEM instructions than the strided l+64q mapping). The 64-lane
// butterfly reduce is permutation-invariant, so the remap is free.
// Negatives processed 4 per iteration (4 independent reduce chains
// interleave on the SIMD); depth-4 prefetch of the next 4 proj rows.
// Per-block partial -> lossP (no atomics).
// ---------------------------------------------------------------------------
__global__ __launch_bounds__(256, 4) void k_loss(const float* __restrict__ ro,
    const float* __restrict__ hU, const float* __restrict__ proj,
    const int* __restrict__ samples, const float* __restrict__ bias_vec,
    const int* __restrict__ data, float* __restrict__ lossP) {
  const int t = threadIdx.x, l = t & 63, w = t >> 6;
  const int p = blockIdx.x * 4 + w;
  const float4 hp4 = ((const float4*)(ro + (size_t)p * 256))[l];
  const float4 hn4 = ((const float4*)(ro + ((size_t)p + 64) * 256))[l];
  const float4 hu4 = ((const float4*)(hU + (size_t)p * 256))[l];
  float x0v;
  {
    float dx = hp4.x - hn4.x, dy = hp4.y - hn4.y;
    float dz = hp4.z - hn4.z, dw = hp4.w - hn4.w;
    float dsq = dx * dx;
    dsq = fmaf(dy, dy, dsq);
    dsq = fmaf(dz, dz, dsq);
    dsq = fmaf(dw, dw, dsq);
#pragma unroll
    for (int m = 1; m < 64; m <<= 1) dsq += __shfl_xor(dsq, m);
    x0v = TEMPC * (bias_vec[data[p]] - dsq);   // positive logit
  }
  int   stok  = (l < 32) ? samples[(size_t)l * SB + p] : 0;
  float sbias = (l < 32) ? bias_vec[stok] : 0.f;

  // prime: rows for negatives 0..3 (one dwordx4 per row per lane)
  float4 cr[4];
#pragma unroll
  for (int m = 0; m < 4; ++m) {
    int tk = __builtin_amdgcn_readlane(stok, m);
    cr[m] = ((const float4*)(proj + (size_t)tk * 256))[l];
  }

  float lg = 0.f;                         // lane n (<32) will hold logit n
  for (int n0 = 0; n0 < 32; n0 += 4) {
    float4 nx[4];
    if (n0 < 28) {                        // issue next 4 rows' loads first
#pragma unroll
      for (int m = 0; m < 4; ++m) {
        int tk = __builtin_amdgcn_readlane(stok, n0 + 4 + m);
        nx[m] = ((const float4*)(proj + (size_t)tk * 256))[l];
      }
    }
    float s[4];
#pragma unroll
    for (int m = 0; m < 4; ++m) {
      float o0 = tanh_fast(cr[m].x + hu4.x);
      float o1 = tanh_fast(cr[m].y + hu4.y);
      float o2 = tanh_fast(cr[m].z + hu4.z);
      float o3 = tanh_fast(cr[m].w + hu4.w);
      float d0 = hp4.x - o0, d1 = hp4.y - o1, d2 = hp4.z - o2, d3 = hp4.w - o3;
      float acc = d0 * d0;
      acc = fmaf(d1, d1, acc);
      acc = fmaf(d2, d2, acc);
      acc = fmaf(d3, d3, acc);
      s[m] = acc;
    }
    // 4 independent butterfly reduces, interleaved
#pragma unroll
    for (int sh = 1; sh < 64; sh <<= 1) {
#pragma unroll
      for (int m = 0; m < 4; ++m) s[m] += __shfl_xor(s[m], sh);
    }
#pragma unroll
    for (int m = 0; m < 4; ++m) {
      float bn = rlf(sbias, n0 + m);
      float logit = TEMPC * (bn - s[m]);
      if (l == n0 + m) lg = logit;
    }
    if (n0 < 28) {
#pragma unroll
      for (int m = 0; m < 4; ++m) cr[m] = nx[m];
    }
  }

  float v = (l < 32) ? lg : ((l == 32) ? x0v : -INFINITY);
  float mx = v;
#pragma unroll
  for (int m = 1; m < 64; m <<= 1) mx = fmaxf(mx, __shfl_xor(mx, m));
  float e = (l < 33) ? __expf(v - mx) : 0.f;
#pragma unroll
  for (int m = 1; m < 64; m <<= 1) e += __shfl_xor(e, m);
  float lse = mx + __logf(e);

  __shared__ float bl[4];
  if (l == 0) bl[w] = lse - x0v;
  __syncthreads();
  if (t == 0) lossP[blockIdx.x] = (bl[0] + bl[1] + bl[2] + bl[3]);
}

// ---------------------------------------------------------------------------
// K4: out[0] = sum(lossP)/8192 + BIAS_REG * sum(bias_vec^2). One block,
// 1024 thr = 16 waves; no atomics anywhere.
// ---------------------------------------------------------------------------
__global__ __launch_bounds__(1024) void k_final(const float* __restrict__ lossP,
    const float* __restrict__ bv, float* __restrict__ out) {
  const int t = threadIdx.x, l = t & 63, w = t >> 6;
  float sa = 0.f;
  for (int i = t; i < 2048; i += 1024) sa += lossP[i];
  float sb = 0.f;
  for (int i = t; i < 12500; i += 1024) {     // 50000 = 12500 float4 exactly
    float4 v = ((const float4*)bv)[i];
    sb += v.x * v.x + v.y * v.y + v.z * v.z + v.w * v.w;
  }
#pragma unroll
  for (int m = 1; m < 64; m <<= 1) {
    sa += __shfl_xor(sa, m);
    sb += __shfl_xor(sb, m);
  }
  __shared__ float wa[16], wb[16];
  if (l == 0) { wa[w] = sa; wb[w] = sb; }
  __syncthreads();
  if (t == 0) {
    float ta = 0.f, tb = 0.f;
#pragma unroll
    for (int i = 0; i < 16; ++i) { ta += wa[i]; tb += wb[i]; }
    out[0] = ta * (1.0f / 8192.0f) + tb;
  }
}

// ---------------------------------------------------------------------------
extern "C" void kernel_launch(void* const* d_in, const int* in_sizes, int n_in,
                              void* d_out, int out_size, void* d_ws, size_t ws_size,
                              hipStream_t stream) {
  const int*   data     = (const int*)  d_in[0];
  const float* hidden   = (const float*)d_in[1];
  const int*   samples  = (const int*)  d_in[2];
  const float* emb      = (const float*)d_in[3];
  const float* W_ih     = (const float*)d_in[4];
  const float* b_ih     = (const float*)d_in[5];
  const float* W_hh     = (const float*)d_in[6];
  const float* b_hh     = (const float*)d_in[7];
  const float* bias_vec = (const float*)d_in[8];
  float* out = (float*)d_out;
  float* ws  = (float*)d_ws;

  // workspace layout (floats): total ~17.08M floats = 68.3 MB
  float* proj  = ws;                      // 50000*256 = 12,800,000
  float* Wt    = proj + 12800000;         // 256*256   = 65,536
  float* ro    = Wt + 65536;              // 129*64*256 = 2,113,536
  float* hU    = ro + 2113536;            // 8192*256  = 2,097,152
  float* lossP = hU + 2097152;            // 2,048

  k_prep <<<256, 256, 0, stream>>>(W_ih, Wt);
  k_proj <<<782, 512, 0, stream>>>(emb, Wt, b_ih, proj, NT);
  k_scan <<<64, 512, 0, stream>>>(proj, data, W_hh, b_hh, hidden, ro, hU, out);
  k_loss <<<2048, 256, 0, stream>>>(ro, hU, proj, samples, bias_vec, data, lossP);
  k_final<<<1, 1024, 0, stream>>>(lossP, bias_vec, out);
}